// Round 5
// baseline (409.890 us; speedup 1.0000x reference)
//
#include <hip/hip_runtime.h>

#define SCALE 0.17677669529663687f

typedef __attribute__((ext_vector_type(8))) short bf16x8;
typedef __attribute__((ext_vector_type(4))) float f32x4;

__device__ inline short cvt_bf16(float f) {          // RNE (prep: weights/q)
    union { float f; unsigned u; } v; v.f = f;
    unsigned r = v.u + 0x7fffu + ((v.u >> 16) & 1u);
    return (short)(r >> 16);
}
__device__ inline short cvt_bf16_fast(float f) {     // round-up-ties, 2 ops
    union { float f; unsigned u; } v; v.f = f;
    return (short)((v.u + 0x8000u) >> 16);
}
__device__ inline unsigned pack_bf16x2(float f0, float f1) {
    union { float f; unsigned u; } a, b; a.f = f0; b.f = f1;
    return __builtin_amdgcn_perm(b.u + 0x8000u, a.u + 0x8000u, 0x07060302u);
}

// ws layout (short elements):
//   [0, 32768)        W_kv^T  bf16 [256][128]
//   [32768, 49152)    W_proj^T bf16 [128][128]
//   [49152, 450560)   q bf16 * SCALE, [64 img][4 h][49 n][32 d]
//   short 450560..    bias fp32 [4 h][49 i][64 jpad]
#define WS_WPT  32768
#define WS_QW   49152
#define WS_BIAS 450560

__global__ void prep_kernel(const float* __restrict__ qg,
                            const float* __restrict__ rbt,
                            const float* __restrict__ wkv,
                            const float* __restrict__ wpj,
                            const int*   __restrict__ ridx,
                            short* __restrict__ ws) {
    int i = blockIdx.x * 256 + threadIdx.x;
    if (i < 32768) {                       // W_kv^T
        int c = i >> 7, k = i & 127;
        ws[i] = cvt_bf16(wkv[k * 256 + c]);
        return;
    }
    i -= 32768;
    if (i < 16384) {                       // W_proj^T
        int c = i >> 7, k = i & 127;
        ws[WS_WPT + i] = cvt_bf16(wpj[k * 128 + c]);
        return;
    }
    i -= 16384;
    if (i < 100352) {                      // q * SCALE, 4 elems/thread
        float4 q4 = *(const float4*)(qg + (long)i * 4);
        unsigned lo = (unsigned)(unsigned short)cvt_bf16(q4.x * SCALE) |
                      ((unsigned)(unsigned short)cvt_bf16(q4.y * SCALE) << 16);
        unsigned hi = (unsigned)(unsigned short)cvt_bf16(q4.z * SCALE) |
                      ((unsigned)(unsigned short)cvt_bf16(q4.w * SCALE) << 16);
        uint2 u; u.x = lo; u.y = hi;
        *(uint2*)(ws + WS_QW + (long)i * 4) = u;
        return;
    }
    i -= 100352;
    if (i < 12544) {                       // bias padded [h][i][64]
        int h = i / 3136, rem = i % 3136, ir = rem >> 6, j = rem & 63;
        float* bias = (float*)(ws + WS_BIAS);
        bias[i] = (j < 49) ? rbt[ridx[ir * 49 + j] * 4 + h] : 0.f;
    }
}

// LDS (shorts), 39552 B total -> 4 blocks/CU:
//  P region [4 heads][3136]: K (64 rows x 40) overlaid by P (49 rows x 64, XOR-swizzled)
//  V^T @12544: [4*32 rows][56]   (toks 0..55; 56..63 never stored, P cols there = 0)
//  tail @19712: 64 zeroed shorts (guards last V row's b128 overread)
//  os  @0: [64][136] overlay for proj stage
#define PSLOT   3136
#define VOFF    12544
#define VSTR    56
#define SMEM_SZ 19776

__global__ __launch_bounds__(256, 4) void win_attn_kernel(
        const float* __restrict__ x,
        const short* __restrict__ ws,
        const float* __restrict__ bkv,
        const float* __restrict__ bpj,
        float* __restrict__ out) {
    const int b    = blockIdx.x;
    const int img  = b >> 6;
    const int tid  = threadIdx.x;
    const int w    = tid >> 6;
    const int lane = tid & 63;
    const int quad = lane >> 4;
    const int l16  = lane & 15;

    const short* wkvt  = ws;
    const short* wpt   = ws + WS_WPT;
    const short* qw    = ws + WS_QW;
    const float* biasb = (const float*)(ws + WS_BIAS);

    __shared__ __align__(16) short smem[SMEM_SZ];
    short* os = smem;

    if (tid < 64) smem[19712 + tid] = 0;   // zero tail guard (before barrier 1)

    const f32x4 fzero = {0.f, 0.f, 0.f, 0.f};
    const int h = w;

    // prefetch q B-frags (global, hidden behind stage 1)
    const short* qh = qw + (long)(img * 4 + h) * 49 * 32;
    bf16x8 qfrag[4];
    #pragma unroll
    for (int ni = 0; ni < 4; ++ni) {
        int i = ni * 16 + l16; if (i > 48) i = 48;
        qfrag[ni] = *(const bf16x8*)(qh + i * 32 + quad * 8);
    }

    // ---------------- Stage 1: kv = x[b] @ W_kv + b_kv ----------------
    // per-nt column tile: acc[4] only (16 regs); x re-loaded per nt (L1/L2 hit)
    const float* xb = x + (long)b * 49 * 128;
    #pragma unroll
    for (int nt = 0; nt < 4; ++nt) {
        const int c0 = (w * 4 + nt) * 16;
        f32x4 acc[4] = {fzero, fzero, fzero, fzero};
        #pragma unroll
        for (int kk = 0; kk < 4; ++kk) {
            bf16x8 bfrag = *(const bf16x8*)(wkvt + (c0 + l16) * 128 + kk * 32 + quad * 8);
            bf16x8 afrag[4];
            #pragma unroll
            for (int mi = 0; mi < 4; ++mi) {
                int tok = mi * 16 + l16; if (tok > 48) tok = 48;
                const float* xr = xb + tok * 128 + kk * 32 + quad * 8;
                float4 a = *(const float4*)xr;
                float4 c = *(const float4*)(xr + 4);
                union { uint4 u; bf16x8 v; } pk;
                pk.u.x = pack_bf16x2(a.x, a.y);
                pk.u.y = pack_bf16x2(a.z, a.w);
                pk.u.z = pack_bf16x2(c.x, c.y);
                pk.u.w = pack_bf16x2(c.z, c.w);
                afrag[mi] = pk.v;
            }
            #pragma unroll
            for (int mi = 0; mi < 4; ++mi)
                acc[mi] = __builtin_amdgcn_mfma_f32_16x16x32_bf16(afrag[mi], bfrag, acc[mi], 0, 0, 0);
        }
        const int c = c0 + l16;
        const float bv = bkv[c];
        if (c < 128) {                     // K: [h][tok stride 40][d]
            int hh = c >> 5, d = c & 31;
            short* kdst = smem + hh * PSLOT + d;
            #pragma unroll
            for (int mi = 0; mi < 4; ++mi)
                #pragma unroll
                for (int r = 0; r < 4; ++r) {
                    int tok = mi * 16 + quad * 4 + r;
                    kdst[tok * 40] = cvt_bf16_fast(acc[mi][r] + bv);
                }
        } else {                           // V^T: [h*32+d][tok], stride 56, packed b32
            int cv = c - 128, hh = cv >> 5, d = cv & 31;
            short* vdst = smem + VOFF + (hh * 32 + d) * VSTR;
            #pragma unroll
            for (int mi = 0; mi < 4; ++mi) {
                int tok0 = mi * 16 + quad * 4;
                if (tok0 < VSTR) {
                    *(unsigned*)(vdst + tok0)     = pack_bf16x2(acc[mi][0] + bv, acc[mi][1] + bv);
                    *(unsigned*)(vdst + tok0 + 2) = pack_bf16x2(acc[mi][2] + bv, acc[mi][3] + bv);
                }
            }
        }
    }
    __syncthreads();

    // ---------------- Stage 2: St = K @ q^T, softmax over j (per-ni) ----------------
    short* ksh = smem + h * PSLOT;
    bf16x8 kfrag[4];
    #pragma unroll
    for (int mi = 0; mi < 4; ++mi)
        kfrag[mi] = *(const bf16x8*)(ksh + (mi * 16 + l16) * 40 + quad * 8);

    #pragma unroll
    for (int ni = 0; ni < 4; ++ni) {
        f32x4 sacc[4] = {fzero, fzero, fzero, fzero};
        #pragma unroll
        for (int mi = 0; mi < 4; ++mi)
            sacc[mi] = __builtin_amdgcn_mfma_f32_16x16x32_bf16(kfrag[mi], qfrag[ni], sacc[mi], 0, 0, 0);

        int itok = ni * 16 + l16;
        int ic = itok > 48 ? 48 : itok;
        const float* bp = biasb + (h * 49 + ic) * 64;
        float v[16];
        #pragma unroll
        for (int mi = 0; mi < 4; ++mi) {
            float4 b4 = *(const float4*)(bp + mi * 16 + quad * 4);
            float bb[4] = {b4.x, b4.y, b4.z, b4.w};
            #pragma unroll
            for (int r = 0; r < 4; ++r) {
                int j = mi * 16 + quad * 4 + r;
                v[mi * 4 + r] = (j < 49) ? (sacc[mi][r] + bb[r]) : -3.0e38f;
            }
        }
        float m = v[0];
        #pragma unroll
        for (int t = 1; t < 16; ++t) m = fmaxf(m, v[t]);
        m = fmaxf(m, __shfl_xor(m, 16, 64));
        m = fmaxf(m, __shfl_xor(m, 32, 64));
        float sum = 0.f;
        #pragma unroll
        for (int t = 0; t < 16; ++t) { float e = __expf(v[t] - m); v[t] = e; sum += e; }
        sum += __shfl_xor(sum, 16, 64);
        sum += __shfl_xor(sum, 32, 64);
        float inv = 1.0f / sum;
        if (itok < 49) {                   // P: swizzled, stride 64 (overlays K slot, own head only)
            #pragma unroll
            for (int mi = 0; mi < 4; ++mi) {
                int jo8 = mi * 2 + (quad >> 1);
                int off = itok * 64 + ((jo8 ^ (itok & 7)) << 3) + ((quad & 1) << 2);
                uint2 u;
                u.x = pack_bf16x2(v[mi * 4 + 0] * inv, v[mi * 4 + 1] * inv);
                u.y = pack_bf16x2(v[mi * 4 + 2] * inv, v[mi * 4 + 3] * inv);
                *(uint2*)(ksh + off) = u;
            }
        }
    }

    // ---------------- Stage 3: O = P @ V ----------------
    f32x4 oacc[4][2];
    #pragma unroll
    for (int mo = 0; mo < 4; ++mo)
        #pragma unroll
        for (int nt = 0; nt < 2; ++nt) oacc[mo][nt] = fzero;
    #pragma unroll
    for (int kk = 0; kk < 2; ++kk) {
        bf16x8 pfrag[4];
        #pragma unroll
        for (int mo = 0; mo < 4; ++mo) {
            int row = mo * 16 + l16; if (row > 48) row = 48;
            int jo8 = kk * 4 + quad;
            pfrag[mo] = *(const bf16x8*)(ksh + row * 64 + ((jo8 ^ (row & 7)) << 3));
        }
        #pragma unroll
        for (int nt = 0; nt < 2; ++nt) {
            bf16x8 vfrag = *(const bf16x8*)(smem + VOFF + (h * 32 + nt * 16 + l16) * VSTR + kk * 32 + quad * 8);
            #pragma unroll
            for (int mo = 0; mo < 4; ++mo)
                oacc[mo][nt] = __builtin_amdgcn_mfma_f32_16x16x32_bf16(pfrag[mo], vfrag, oacc[mo][nt], 0, 0, 0);
        }
    }
    __syncthreads();   // all waves done reading P/V before os overlay

    #pragma unroll
    for (int mo = 0; mo < 4; ++mo)
        #pragma unroll
        for (int nt = 0; nt < 2; ++nt)
            #pragma unroll
            for (int r = 0; r < 4; ++r) {
                int tok = mo * 16 + quad * 4 + r;
                os[tok * 136 + h * 32 + nt * 16 + l16] = cvt_bf16_fast(oacc[mo][nt][r]);
            }
    __syncthreads();

    // ---------------- Stage 4: out = O @ W_proj + b_proj (kk-outer, low pressure) ----------------
    f32x4 pacc[2][4];
    #pragma unroll
    for (int ct = 0; ct < 2; ++ct)
        #pragma unroll
        for (int mi = 0; mi < 4; ++mi) pacc[ct][mi] = fzero;
    #pragma unroll
    for (int kk = 0; kk < 4; ++kk) {
        bf16x8 ofrag[4];
        #pragma unroll
        for (int mi = 0; mi < 4; ++mi)
            ofrag[mi] = *(const bf16x8*)(os + (mi * 16 + l16) * 136 + kk * 32 + quad * 8);
        #pragma unroll
        for (int ct = 0; ct < 2; ++ct) {
            const int c0 = (w * 2 + ct) * 16;
            bf16x8 wfrag = *(const bf16x8*)(wpt + (c0 + l16) * 128 + kk * 32 + quad * 8);
            #pragma unroll
            for (int mi = 0; mi < 4; ++mi)
                pacc[ct][mi] = __builtin_amdgcn_mfma_f32_16x16x32_bf16(ofrag[mi], wfrag, pacc[ct][mi], 0, 0, 0);
        }
    }
    #pragma unroll
    for (int ct = 0; ct < 2; ++ct) {
        const int c0 = (w * 2 + ct) * 16;
        const float bb = bpj[c0 + l16];
        #pragma unroll
        for (int mi = 0; mi < 4; ++mi)
            #pragma unroll
            for (int r = 0; r < 4; ++r) {
                int tok = mi * 16 + quad * 4 + r;
                if (tok < 49)
                    out[((long)b * 49 + tok) * 128 + c0 + l16] = pacc[ct][mi][r] + bb;
            }
    }
}

extern "C" void kernel_launch(void* const* d_in, const int* in_sizes, int n_in,
                              void* d_out, int out_size, void* d_ws, size_t ws_size,
                              hipStream_t stream) {
    const float* x    = (const float*)d_in[0];
    const float* qg   = (const float*)d_in[1];
    const float* rbt  = (const float*)d_in[2];
    const float* wkv  = (const float*)d_in[3];
    const float* bkv  = (const float*)d_in[4];
    const float* wpj  = (const float*)d_in[5];
    const float* bpj  = (const float*)d_in[6];
    const int*   ridx = (const int*)d_in[7];
    short* ws = (short*)d_ws;

    const int prep_total = 32768 + 16384 + 100352 + 12544;
    prep_kernel<<<(prep_total + 255) / 256, 256, 0, stream>>>(qg, rbt, wkv, wpj, ridx, ws);
    win_attn_kernel<<<4096, 256, 0, stream>>>(x, ws, bkv, bpj, (float*)d_out);
}

// Round 6
// 251.565 us; speedup vs baseline: 1.6294x; 1.6294x over previous
//
#include <hip/hip_runtime.h>

#define SCALE 0.17677669529663687f

typedef __attribute__((ext_vector_type(8))) short bf16x8;
typedef __attribute__((ext_vector_type(4))) float f32x4;

__device__ inline short cvt_bf16(float f) {          // RNE (prep: weights/q)
    union { float f; unsigned u; } v; v.f = f;
    unsigned r = v.u + 0x7fffu + ((v.u >> 16) & 1u);
    return (short)(r >> 16);
}
__device__ inline short cvt_bf16_fast(float f) {     // round-up-ties, 2 ops
    union { float f; unsigned u; } v; v.f = f;
    return (short)((v.u + 0x8000u) >> 16);
}
__device__ inline unsigned pack_bf16x2(float f0, float f1) {
    union { float f; unsigned u; } a, b; a.f = f0; b.f = f1;
    return __builtin_amdgcn_perm(b.u + 0x8000u, a.u + 0x8000u, 0x07060302u);
}

// ws layout (short elements):
//   [0, 32768)        W_kv^T  bf16 [256][128]
//   [32768, 49152)    W_proj^T bf16 [128][128]
//   [49152, 450560)   q bf16 * SCALE, [64 img][4 h][49 n][32 d]
//   short 450560..    bias fp32 [4 h][49 i][64 jpad]
#define WS_WPT  32768
#define WS_QW   49152
#define WS_BIAS 450560

__global__ void prep_kernel(const float* __restrict__ qg,
                            const float* __restrict__ rbt,
                            const float* __restrict__ wkv,
                            const float* __restrict__ wpj,
                            const int*   __restrict__ ridx,
                            short* __restrict__ ws) {
    int i = blockIdx.x * 256 + threadIdx.x;
    if (i < 32768) {                       // W_kv^T
        int c = i >> 7, k = i & 127;
        ws[i] = cvt_bf16(wkv[k * 256 + c]);
        return;
    }
    i -= 32768;
    if (i < 16384) {                       // W_proj^T
        int c = i >> 7, k = i & 127;
        ws[WS_WPT + i] = cvt_bf16(wpj[k * 128 + c]);
        return;
    }
    i -= 16384;
    if (i < 100352) {                      // q * SCALE, 4 elems/thread
        float4 q4 = *(const float4*)(qg + (long)i * 4);
        unsigned lo = (unsigned)(unsigned short)cvt_bf16(q4.x * SCALE) |
                      ((unsigned)(unsigned short)cvt_bf16(q4.y * SCALE) << 16);
        unsigned hi = (unsigned)(unsigned short)cvt_bf16(q4.z * SCALE) |
                      ((unsigned)(unsigned short)cvt_bf16(q4.w * SCALE) << 16);
        uint2 u; u.x = lo; u.y = hi;
        *(uint2*)(ws + WS_QW + (long)i * 4) = u;
        return;
    }
    i -= 100352;
    if (i < 12544) {                       // bias padded [h][i][64]
        int h = i / 3136, rem = i % 3136, ir = rem >> 6, j = rem & 63;
        float* bias = (float*)(ws + WS_BIAS);
        bias[i] = (j < 49) ? rbt[ridx[ir * 49 + j] * 4 + h] : 0.f;
    }
}

// LDS (shorts), 39552 B -> 4 blocks/CU. Time-multiplexed regions:
//  xs @0: x as bf16 [64][136] (rows 0..48) -- stage 0/1 only, dead before K written
//  K/P @0: [4 heads][3136]: K (64 rows x 40) overlaid by P (49 rows x 64, XOR-swizzled)
//  V^T @12544: [4*32 rows][56]
//  tail @19712: 64 zeroed shorts (guards last V row's b128 overread)
//  os @0: [64][136] (stages 3-4)
#define PSLOT   3136
#define VOFF    12544
#define VSTR    56
#define SMEM_SZ 19776

__global__ __launch_bounds__(256, 4) void win_attn_kernel(
        const float* __restrict__ x,
        const short* __restrict__ ws,
        const float* __restrict__ bkv,
        const float* __restrict__ bpj,
        float* __restrict__ out) {
    const int b    = blockIdx.x;
    const int img  = b >> 6;
    const int tid  = threadIdx.x;
    const int w    = tid >> 6;
    const int lane = tid & 63;
    const int quad = lane >> 4;
    const int l16  = lane & 15;

    const short* wkvt  = ws;
    const short* wpt   = ws + WS_WPT;
    const short* qw    = ws + WS_QW;
    const float* biasb = (const float*)(ws + WS_BIAS);

    __shared__ __align__(16) short smem[SMEM_SZ];
    short* xs = smem;                      // [64][136] bf16 x
    short* os = smem;

    if (tid < 64) smem[19712 + tid] = 0;   // zero tail guard

    const f32x4 fzero = {0.f, 0.f, 0.f, 0.f};
    const int h = w;

    // ---------------- Stage 0: x -> bf16 -> LDS [49][136-stride] ----------------
    const float* xb = x + (long)b * 49 * 128;
    #pragma unroll
    for (int it = 0; it < 4; ++it) {
        int chunk = tid + it * 256;        // 784 chunks = 49 rows x 16 col8-groups
        if (chunk < 784) {
            int row = chunk >> 4, c8 = (chunk & 15) * 8;
            const float* p = xb + row * 128 + c8;
            float4 a = *(const float4*)p;
            float4 c = *(const float4*)(p + 4);
            union { uint4 u; bf16x8 v; } pk;
            pk.u.x = pack_bf16x2(a.x, a.y);
            pk.u.y = pack_bf16x2(a.z, a.w);
            pk.u.z = pack_bf16x2(c.x, c.y);
            pk.u.w = pack_bf16x2(c.z, c.w);
            *(bf16x8*)(xs + row * 136 + c8) = pk.v;
        }
    }
    __syncthreads();

    // ---------------- Stage 1: kv = x[b] @ W_kv + b_kv (afrag from LDS) ----------------
    f32x4 acc[4][4];                       // [nt][mi]
    #pragma unroll
    for (int nt = 0; nt < 4; ++nt)
        #pragma unroll
        for (int mi = 0; mi < 4; ++mi) acc[nt][mi] = fzero;

    #pragma unroll
    for (int kk = 0; kk < 4; ++kk) {
        bf16x8 bfr[4];
        #pragma unroll
        for (int nt = 0; nt < 4; ++nt)
            bfr[nt] = *(const bf16x8*)(wkvt + ((w * 4 + nt) * 16 + l16) * 128 + kk * 32 + quad * 8);
        #pragma unroll
        for (int mi = 0; mi < 4; ++mi) {
            int tok = mi * 16 + l16; if (tok > 48) tok = 48;
            bf16x8 af = *(const bf16x8*)(xs + tok * 136 + kk * 32 + quad * 8);
            #pragma unroll
            for (int nt = 0; nt < 4; ++nt)
                acc[nt][mi] = __builtin_amdgcn_mfma_f32_16x16x32_bf16(af, bfr[nt], acc[nt][mi], 0, 0, 0);
        }
    }
    __syncthreads();   // all MFMA reads of xs done before K overwrites it

    #pragma unroll
    for (int nt = 0; nt < 4; ++nt) {
        const int c = (w * 4 + nt) * 16 + l16;
        const float bv = bkv[c];
        if (c < 128) {                     // K: [h][tok stride 40][d]
            int hh = c >> 5, d = c & 31;
            short* kdst = smem + hh * PSLOT + d;
            #pragma unroll
            for (int mi = 0; mi < 4; ++mi)
                #pragma unroll
                for (int r = 0; r < 4; ++r) {
                    int tok = mi * 16 + quad * 4 + r;
                    kdst[tok * 40] = cvt_bf16_fast(acc[nt][mi][r] + bv);
                }
        } else {                           // V^T: [h*32+d][tok], stride 56, packed b32
            int cv = c - 128, hh = cv >> 5, d = cv & 31;
            short* vdst = smem + VOFF + (hh * 32 + d) * VSTR;
            #pragma unroll
            for (int mi = 0; mi < 4; ++mi) {
                int tok0 = mi * 16 + quad * 4;
                if (tok0 < VSTR) {
                    *(unsigned*)(vdst + tok0)     = pack_bf16x2(acc[nt][mi][0] + bv, acc[nt][mi][1] + bv);
                    *(unsigned*)(vdst + tok0 + 2) = pack_bf16x2(acc[nt][mi][2] + bv, acc[nt][mi][3] + bv);
                }
            }
        }
    }
    __syncthreads();

    // ---------------- Stage 2: St = K @ q^T, softmax over j (per-ni) ----------------
    short* ksh = smem + h * PSLOT;
    const short* qh = qw + (long)(img * 4 + h) * 49 * 32;
    bf16x8 qfrag[4];
    #pragma unroll
    for (int ni = 0; ni < 4; ++ni) {
        int i = ni * 16 + l16; if (i > 48) i = 48;
        qfrag[ni] = *(const bf16x8*)(qh + i * 32 + quad * 8);
    }
    bf16x8 kfrag[4];
    #pragma unroll
    for (int mi = 0; mi < 4; ++mi)
        kfrag[mi] = *(const bf16x8*)(ksh + (mi * 16 + l16) * 40 + quad * 8);

    #pragma unroll
    for (int ni = 0; ni < 4; ++ni) {
        f32x4 sacc[4] = {fzero, fzero, fzero, fzero};
        #pragma unroll
        for (int mi = 0; mi < 4; ++mi)
            sacc[mi] = __builtin_amdgcn_mfma_f32_16x16x32_bf16(kfrag[mi], qfrag[ni], sacc[mi], 0, 0, 0);

        int itok = ni * 16 + l16;
        int ic = itok > 48 ? 48 : itok;
        const float* bp = biasb + (h * 49 + ic) * 64;
        float v[16];
        #pragma unroll
        for (int mi = 0; mi < 4; ++mi) {
            float4 b4 = *(const float4*)(bp + mi * 16 + quad * 4);
            float bb[4] = {b4.x, b4.y, b4.z, b4.w};
            #pragma unroll
            for (int r = 0; r < 4; ++r) {
                int j = mi * 16 + quad * 4 + r;
                v[mi * 4 + r] = (j < 49) ? (sacc[mi][r] + bb[r]) : -3.0e38f;
            }
        }
        float m = v[0];
        #pragma unroll
        for (int t = 1; t < 16; ++t) m = fmaxf(m, v[t]);
        m = fmaxf(m, __shfl_xor(m, 16, 64));
        m = fmaxf(m, __shfl_xor(m, 32, 64));
        float sum = 0.f;
        #pragma unroll
        for (int t = 0; t < 16; ++t) { float e = __expf(v[t] - m); v[t] = e; sum += e; }
        sum += __shfl_xor(sum, 16, 64);
        sum += __shfl_xor(sum, 32, 64);
        float inv = 1.0f / sum;
        if (itok < 49) {                   // P: swizzled, stride 64 (own head's slot only)
            #pragma unroll
            for (int mi = 0; mi < 4; ++mi) {
                int jo8 = mi * 2 + (quad >> 1);
                int off = itok * 64 + ((jo8 ^ (itok & 7)) << 3) + ((quad & 1) << 2);
                uint2 u;
                u.x = pack_bf16x2(v[mi * 4 + 0] * inv, v[mi * 4 + 1] * inv);
                u.y = pack_bf16x2(v[mi * 4 + 2] * inv, v[mi * 4 + 3] * inv);
                *(uint2*)(ksh + off) = u;
            }
        }
    }

    // ---------------- Stage 3: O = P @ V ----------------
    f32x4 oacc[4][2];
    #pragma unroll
    for (int mo = 0; mo < 4; ++mo)
        #pragma unroll
        for (int nt = 0; nt < 2; ++nt) oacc[mo][nt] = fzero;
    #pragma unroll
    for (int kk = 0; kk < 2; ++kk) {
        bf16x8 pfrag[4];
        #pragma unroll
        for (int mo = 0; mo < 4; ++mo) {
            int row = mo * 16 + l16; if (row > 48) row = 48;
            int jo8 = kk * 4 + quad;
            pfrag[mo] = *(const bf16x8*)(ksh + row * 64 + ((jo8 ^ (row & 7)) << 3));
        }
        #pragma unroll
        for (int nt = 0; nt < 2; ++nt) {
            bf16x8 vfrag = *(const bf16x8*)(smem + VOFF + (h * 32 + nt * 16 + l16) * VSTR + kk * 32 + quad * 8);
            #pragma unroll
            for (int mo = 0; mo < 4; ++mo)
                oacc[mo][nt] = __builtin_amdgcn_mfma_f32_16x16x32_bf16(pfrag[mo], vfrag, oacc[mo][nt], 0, 0, 0);
        }
    }
    __syncthreads();   // all waves done reading P/V before os overlay

    #pragma unroll
    for (int mo = 0; mo < 4; ++mo)
        #pragma unroll
        for (int nt = 0; nt < 2; ++nt)
            #pragma unroll
            for (int r = 0; r < 4; ++r) {
                int tok = mo * 16 + quad * 4 + r;
                os[tok * 136 + h * 32 + nt * 16 + l16] = cvt_bf16_fast(oacc[mo][nt][r]);
            }
    __syncthreads();

    // ---------------- Stage 4: out = O @ W_proj + b_proj (kk-outer) ----------------
    f32x4 pacc[2][4];
    #pragma unroll
    for (int ct = 0; ct < 2; ++ct)
        #pragma unroll
        for (int mi = 0; mi < 4; ++mi) pacc[ct][mi] = fzero;
    #pragma unroll
    for (int kk = 0; kk < 4; ++kk) {
        bf16x8 ofrag[4];
        #pragma unroll
        for (int mi = 0; mi < 4; ++mi)
            ofrag[mi] = *(const bf16x8*)(os + (mi * 16 + l16) * 136 + kk * 32 + quad * 8);
        #pragma unroll
        for (int ct = 0; ct < 2; ++ct) {
            const int c0 = (w * 2 + ct) * 16;
            bf16x8 wfrag = *(const bf16x8*)(wpt + (c0 + l16) * 128 + kk * 32 + quad * 8);
            #pragma unroll
            for (int mi = 0; mi < 4; ++mi)
                pacc[ct][mi] = __builtin_amdgcn_mfma_f32_16x16x32_bf16(ofrag[mi], wfrag, pacc[ct][mi], 0, 0, 0);
        }
    }
    #pragma unroll
    for (int ct = 0; ct < 2; ++ct) {
        const int c0 = (w * 2 + ct) * 16;
        const float bb = bpj[c0 + l16];
        #pragma unroll
        for (int mi = 0; mi < 4; ++mi)
            #pragma unroll
            for (int r = 0; r < 4; ++r) {
                int tok = mi * 16 + quad * 4 + r;
                if (tok < 49)
                    out[((long)b * 49 + tok) * 128 + c0 + l16] = pacc[ct][mi][r] + bb;
            }
    }
}

extern "C" void kernel_launch(void* const* d_in, const int* in_sizes, int n_in,
                              void* d_out, int out_size, void* d_ws, size_t ws_size,
                              hipStream_t stream) {
    const float* x    = (const float*)d_in[0];
    const float* qg   = (const float*)d_in[1];
    const float* rbt  = (const float*)d_in[2];
    const float* wkv  = (const float*)d_in[3];
    const float* bkv  = (const float*)d_in[4];
    const float* wpj  = (const float*)d_in[5];
    const float* bpj  = (const float*)d_in[6];
    const int*   ridx = (const int*)d_in[7];
    short* ws = (short*)d_ws;

    const int prep_total = 32768 + 16384 + 100352 + 12544;
    prep_kernel<<<(prep_total + 255) / 256, 256, 0, stream>>>(qg, rbt, wkv, wpj, ridx, ws);
    win_attn_kernel<<<4096, 256, 0, stream>>>(x, ws, bkv, bpj, (float*)d_out);
}